// Round 1
// baseline (955.402 us; speedup 1.0000x reference)
//
#include <hip/hip_runtime.h>
#include <hip/hip_bf16.h>

typedef short s16x8 __attribute__((ext_vector_type(8)));
typedef float f32x4 __attribute__((ext_vector_type(4)));
typedef unsigned short ushort8 __attribute__((ext_vector_type(8)));

#define T_TOK 8192
#define DDIM 1024
#define NEXP 8
#define FDIM 4096
#define BM 128
#define BN 128
#define BK 32
#define LDK 40   // padded LDS K-stride (elems): 80B -> 2-way-max bank aliasing
#define MAXT 144
#define PADMAX (16384 + NEXP * BM)

__device__ __forceinline__ float gelu_tanh(float x) {
  float u = 0.7978845608028654f * (x + 0.044715f * x * x * x);
  return 0.5f * x * (1.0f + tanhf(u));
}

// ---------------- gating: logits -> top2 -> weights + counts ----------------
__global__ __launch_bounds__(256) void gate_kernel(
    const float* __restrict__ x, const float* __restrict__ gw,
    int* __restrict__ counts, int* __restrict__ tok_e, float* __restrict__ tok_w)
{
  int lane = threadIdx.x & 63;
  int tok = blockIdx.x * 4 + (threadIdx.x >> 6);
  const float* xr = x + (size_t)tok * DDIM;
  float acc[NEXP];
#pragma unroll
  for (int e = 0; e < NEXP; ++e) acc[e] = 0.f;
  for (int i = 0; i < DDIM / 64; ++i) {
    int d = i * 64 + lane;
    float xv = xr[d];
    const float* g = gw + (size_t)d * NEXP;
#pragma unroll
    for (int e = 0; e < NEXP; ++e) acc[e] += xv * g[e];
  }
#pragma unroll
  for (int off = 32; off > 0; off >>= 1) {
#pragma unroll
    for (int e = 0; e < NEXP; ++e) acc[e] += __shfl_xor(acc[e], off);
  }
  if (lane == 0) {
    int i1 = 0; float m1 = acc[0];
#pragma unroll
    for (int e = 1; e < NEXP; ++e) if (acc[e] > m1) { m1 = acc[e]; i1 = e; }
    int i2 = -1; float m2 = -3.4e38f;
#pragma unroll
    for (int e = 0; e < NEXP; ++e) if (e != i1 && acc[e] > m2) { m2 = acc[e]; i2 = e; }
    float w1 = 1.f / (1.f + expf(m2 - m1));   // == p1/(p1+p2)
    tok_e[tok * 2] = i1; tok_e[tok * 2 + 1] = i2;
    tok_w[tok * 2] = w1; tok_w[tok * 2 + 1] = 1.f - w1;
    atomicAdd(&counts[i1], 1);
    atomicAdd(&counts[i2], 1);
  }
}

// ---------------- scan: padded offsets + tile table ----------------
__global__ void scan_kernel(const int* __restrict__ counts, int* padded_off,
                            int* tile_e, int* tile_row, int* numTiles)
{
  if (threadIdx.x == 0 && blockIdx.x == 0) {
    int off = 0, nt = 0;
    for (int e = 0; e < NEXP; ++e) {
      padded_off[e] = off;
      int c = counts[e];
      int ntile = (c + BM - 1) / BM;
      for (int i = 0; i < ntile; ++i) { tile_e[nt] = e; tile_row[nt] = off + i * BM; ++nt; }
      off += ntile * BM;
    }
    *numTiles = nt;
  }
}

__global__ void init_pairs(int* __restrict__ pair_token, float* __restrict__ pair_w) {
  int i = blockIdx.x * 256 + threadIdx.x;
  if (i < PADMAX) { pair_token[i] = -1; pair_w[i] = 0.f; }
}

__global__ void scatter_kernel(const int* __restrict__ tok_e, const float* __restrict__ tok_w,
                               const int* __restrict__ padded_off, int* __restrict__ fill,
                               int* __restrict__ pair_token, float* __restrict__ pair_w)
{
  int tok = blockIdx.x * 256 + threadIdx.x;
  if (tok >= T_TOK) return;
#pragma unroll
  for (int k = 0; k < 2; ++k) {
    int e = tok_e[tok * 2 + k];
    int slot = padded_off[e] + atomicAdd(&fill[e], 1);
    pair_token[slot] = tok;
    pair_w[slot] = tok_w[tok * 2 + k];
  }
}

// ---------------- gather tokens -> bf16 rows (zeros for padding) ----------------
__global__ __launch_bounds__(256) void gather_x(
    const float* __restrict__ x, const int* __restrict__ pair_token,
    __hip_bfloat16* __restrict__ Xg)
{
  int gid = blockIdx.x * 256 + threadIdx.x;
  int r = gid >> 7;
  int c = (gid & 127) << 3;
  if (r >= PADMAX) return;
  int tk = pair_token[r];
  __hip_bfloat16 v[8];
  if (tk < 0) {
#pragma unroll
    for (int j = 0; j < 8; ++j) v[j] = __float2bfloat16(0.f);
  } else {
    const float* src = x + (size_t)tk * DDIM + c;
#pragma unroll
    for (int j = 0; j < 8; ++j) v[j] = __float2bfloat16(src[j]);
  }
  *(ushort8*)(Xg + (size_t)r * DDIM + c) = *(const ushort8*)v;
}

// ---------------- fp32 (R,C) -> bf16 (C,R) transpose+convert, per expert z ----------------
__global__ void transpose_conv(const float* __restrict__ in, __hip_bfloat16* __restrict__ out,
                               int R, int C)
{
  __shared__ __hip_bfloat16 tile[32][33];
  size_t mat = (size_t)R * C;
  const float* ip = in + (size_t)blockIdx.z * mat;
  __hip_bfloat16* op = out + (size_t)blockIdx.z * mat;
  int c0 = blockIdx.x * 32, r0 = blockIdx.y * 32;
#pragma unroll
  for (int i = 0; i < 4; ++i) {
    int r = r0 + threadIdx.y + i * 8;
    tile[threadIdx.y + i * 8][threadIdx.x] =
        __float2bfloat16(ip[(size_t)r * C + c0 + threadIdx.x]);
  }
  __syncthreads();
#pragma unroll
  for (int i = 0; i < 4; ++i) {
    int cc = c0 + threadIdx.y + i * 8;
    op[(size_t)cc * R + r0 + threadIdx.x] = tile[threadIdx.x][threadIdx.y + i * 8];
  }
}

// ---------------- pass A: H = gelu(Xg @ W1[e]) ----------------
__global__ __launch_bounds__(256) void ffn1_kernel(
    const __hip_bfloat16* __restrict__ Xg, const __hip_bfloat16* __restrict__ W1t,
    __hip_bfloat16* __restrict__ H,
    const int* __restrict__ tile_e, const int* __restrict__ tile_row,
    const int* __restrict__ numTiles)
{
  if ((int)blockIdx.x >= *numTiles) return;
  int e = tile_e[blockIdx.x];
  int row0 = tile_row[blockIdx.x];
  int col0 = blockIdx.y * BN;
  __shared__ __align__(16) __hip_bfloat16 aS[BM][LDK];
  __shared__ __align__(16) __hip_bfloat16 bS[BN][LDK];
  int t = threadIdx.x, lane = t & 63, wid = t >> 6;
  int wr = (wid >> 1) * 64, wc = (wid & 1) * 64;
  f32x4 acc[4][4] = {};
  const __hip_bfloat16* Ab = Xg + (size_t)row0 * DDIM;
  const __hip_bfloat16* Bb = W1t + ((size_t)e * FDIM + col0) * DDIM;
  int sr = t >> 1, sc = (t & 1) * 16;
  int fr = lane & 15, fk = (lane >> 4) * 8;
  for (int kt = 0; kt < DDIM; kt += BK) {
    ushort8 a0 = *(const ushort8*)(Ab + (size_t)sr * DDIM + kt + sc);
    ushort8 a1 = *(const ushort8*)(Ab + (size_t)sr * DDIM + kt + sc + 8);
    ushort8 b0 = *(const ushort8*)(Bb + (size_t)sr * DDIM + kt + sc);
    ushort8 b1 = *(const ushort8*)(Bb + (size_t)sr * DDIM + kt + sc + 8);
    __syncthreads();
    *(ushort8*)&aS[sr][sc] = a0; *(ushort8*)&aS[sr][sc + 8] = a1;
    *(ushort8*)&bS[sr][sc] = b0; *(ushort8*)&bS[sr][sc + 8] = b1;
    __syncthreads();
    s16x8 af[4], bfr[4];
#pragma unroll
    for (int m = 0; m < 4; ++m) af[m] = *(const s16x8*)&aS[wr + m * 16 + fr][fk];
#pragma unroll
    for (int n = 0; n < 4; ++n) bfr[n] = *(const s16x8*)&bS[wc + n * 16 + fr][fk];
#pragma unroll
    for (int m = 0; m < 4; ++m)
#pragma unroll
      for (int n = 0; n < 4; ++n)
        acc[m][n] = __builtin_amdgcn_mfma_f32_16x16x32_bf16(af[m], bfr[n], acc[m][n], 0, 0, 0);
  }
  int orow = (lane >> 4) * 4;
#pragma unroll
  for (int m = 0; m < 4; ++m) {
    int r = row0 + wr + m * 16 + orow;
#pragma unroll
    for (int n = 0; n < 4; ++n) {
      int cidx = col0 + wc + n * 16 + fr;
#pragma unroll
      for (int j = 0; j < 4; ++j)
        H[(size_t)(r + j) * FDIM + cidx] = __float2bfloat16(gelu_tanh(acc[m][n][j]));
    }
  }
}

// ---------------- pass B: out += w * (H @ W2[e]) ----------------
__global__ __launch_bounds__(256) void ffn2_kernel(
    const __hip_bfloat16* __restrict__ H, const __hip_bfloat16* __restrict__ W2t,
    float* __restrict__ out,
    const int* __restrict__ tile_e, const int* __restrict__ tile_row,
    const int* __restrict__ numTiles,
    const int* __restrict__ pair_token, const float* __restrict__ pair_w)
{
  if ((int)blockIdx.x >= *numTiles) return;
  int e = tile_e[blockIdx.x];
  int row0 = tile_row[blockIdx.x];
  int col0 = blockIdx.y * BN;
  __shared__ __align__(16) __hip_bfloat16 aS[BM][LDK];
  __shared__ __align__(16) __hip_bfloat16 bS[BN][LDK];
  int t = threadIdx.x, lane = t & 63, wid = t >> 6;
  int wr = (wid >> 1) * 64, wc = (wid & 1) * 64;
  f32x4 acc[4][4] = {};
  const __hip_bfloat16* Ab = H + (size_t)row0 * FDIM;
  const __hip_bfloat16* Bb = W2t + ((size_t)e * DDIM + col0) * FDIM;
  int sr = t >> 1, sc = (t & 1) * 16;
  int fr = lane & 15, fk = (lane >> 4) * 8;
  for (int kt = 0; kt < FDIM; kt += BK) {
    ushort8 a0 = *(const ushort8*)(Ab + (size_t)sr * FDIM + kt + sc);
    ushort8 a1 = *(const ushort8*)(Ab + (size_t)sr * FDIM + kt + sc + 8);
    ushort8 b0 = *(const ushort8*)(Bb + (size_t)sr * FDIM + kt + sc);
    ushort8 b1 = *(const ushort8*)(Bb + (size_t)sr * FDIM + kt + sc + 8);
    __syncthreads();
    *(ushort8*)&aS[sr][sc] = a0; *(ushort8*)&aS[sr][sc + 8] = a1;
    *(ushort8*)&bS[sr][sc] = b0; *(ushort8*)&bS[sr][sc + 8] = b1;
    __syncthreads();
    s16x8 af[4], bfr[4];
#pragma unroll
    for (int m = 0; m < 4; ++m) af[m] = *(const s16x8*)&aS[wr + m * 16 + fr][fk];
#pragma unroll
    for (int n = 0; n < 4; ++n) bfr[n] = *(const s16x8*)&bS[wc + n * 16 + fr][fk];
#pragma unroll
    for (int m = 0; m < 4; ++m)
#pragma unroll
      for (int n = 0; n < 4; ++n)
        acc[m][n] = __builtin_amdgcn_mfma_f32_16x16x32_bf16(af[m], bfr[n], acc[m][n], 0, 0, 0);
  }
  int orow = (lane >> 4) * 4;
#pragma unroll
  for (int m = 0; m < 4; ++m) {
    int rbase = row0 + wr + m * 16 + orow;
#pragma unroll
    for (int j = 0; j < 4; ++j) {
      int r = rbase + j;
      int tk = pair_token[r];
      if (tk < 0) continue;
      float w = pair_w[r];
      float* op = out + (size_t)tk * DDIM + col0 + wc;
#pragma unroll
      for (int n = 0; n < 4; ++n)
        atomicAdd(op + n * 16 + fr, w * acc[m][n][j]);
    }
  }
}

extern "C" void kernel_launch(void* const* d_in, const int* in_sizes, int n_in,
                              void* d_out, int out_size, void* d_ws, size_t ws_size,
                              hipStream_t stream)
{
  const float* x      = (const float*)d_in[0];
  const float* gate_w = (const float*)d_in[1];
  const float* w1     = (const float*)d_in[2];
  const float* w2     = (const float*)d_in[3];
  float* out = (float*)d_out;

  char* ws = (char*)d_ws;
  size_t off = 0;
  auto alloc = [&](size_t bytes) -> void* {
    void* p = ws + off;
    off = (off + bytes + 255) & ~(size_t)255;
    return p;
  };
  int*   counts     = (int*)alloc(NEXP * 4);
  int*   fill       = (int*)alloc(NEXP * 4);
  int*   padded_off = (int*)alloc(NEXP * 4);
  int*   numTiles   = (int*)alloc(4);
  int*   tile_e     = (int*)alloc(MAXT * 4);
  int*   tile_row   = (int*)alloc(MAXT * 4);
  int*   tok_e      = (int*)alloc((size_t)T_TOK * 2 * 4);
  float* tok_w      = (float*)alloc((size_t)T_TOK * 2 * 4);
  int*   pair_token = (int*)alloc((size_t)PADMAX * 4);
  float* pair_w     = (float*)alloc((size_t)PADMAX * 4);
  __hip_bfloat16* Xg   = (__hip_bfloat16*)alloc((size_t)PADMAX * DDIM * 2);
  __hip_bfloat16* W1t  = (__hip_bfloat16*)alloc((size_t)NEXP * FDIM * DDIM * 2);
  __hip_bfloat16* W2t  = (__hip_bfloat16*)alloc((size_t)NEXP * FDIM * DDIM * 2);
  __hip_bfloat16* Hbuf = (__hip_bfloat16*)alloc((size_t)PADMAX * FDIM * 2);
  (void)in_sizes; (void)n_in; (void)ws_size;

  // zero the small control block (counts/fill/padded_off/numTiles live in first 1KB)
  hipMemsetAsync(d_ws, 0, 1024, stream);
  hipMemsetAsync(d_out, 0, (size_t)out_size * sizeof(float), stream);

  dim3 tb(32, 8);
  transpose_conv<<<dim3(FDIM / 32, DDIM / 32, NEXP), tb, 0, stream>>>(w1, W1t, DDIM, FDIM);
  transpose_conv<<<dim3(DDIM / 32, FDIM / 32, NEXP), tb, 0, stream>>>(w2, W2t, FDIM, DDIM);

  gate_kernel<<<T_TOK / 4, 256, 0, stream>>>(x, gate_w, counts, tok_e, tok_w);
  scan_kernel<<<1, 64, 0, stream>>>(counts, padded_off, tile_e, tile_row, numTiles);
  init_pairs<<<(PADMAX + 255) / 256, 256, 0, stream>>>(pair_token, pair_w);
  scatter_kernel<<<T_TOK / 256, 256, 0, stream>>>(tok_e, tok_w, padded_off, fill,
                                                  pair_token, pair_w);
  gather_x<<<(PADMAX * (DDIM / 8) + 255) / 256, 256, 0, stream>>>(x, pair_token, Xg);

  ffn1_kernel<<<dim3(MAXT, FDIM / BN), 256, 0, stream>>>(Xg, W1t, Hbuf,
                                                         tile_e, tile_row, numTiles);
  ffn2_kernel<<<dim3(MAXT, DDIM / BN), 256, 0, stream>>>(Hbuf, W2t, out,
                                                         tile_e, tile_row, numTiles,
                                                         pair_token, pair_w);
}

// Round 2
// 873.137 us; speedup vs baseline: 1.0942x; 1.0942x over previous
//
#include <hip/hip_runtime.h>
#include <hip/hip_bf16.h>

typedef short s16x8 __attribute__((ext_vector_type(8)));
typedef float f32x4 __attribute__((ext_vector_type(4)));
typedef unsigned short us8 __attribute__((ext_vector_type(8)));
typedef unsigned short us4 __attribute__((ext_vector_type(4)));

#define T_TOK 8192
#define DDIM 1024
#define NEXP 8
#define FDIM 4096
#define BM 128
#define BN 128
#define BKK 64
#define MAXT 144
#define PADMAX (16384 + NEXP * BM)

#define GLOAD16(dst, src) \
  __builtin_amdgcn_global_load_lds((const __attribute__((address_space(1))) unsigned int*)(src), \
                                   (__attribute__((address_space(3))) unsigned int*)(dst), 16, 0, 0)

__device__ __forceinline__ float gelu_tanh(float x) {
  float u = 0.7978845608028654f * (x + 0.044715f * x * x * x);
  return 0.5f * x * (1.0f + tanhf(u));
}
__device__ __forceinline__ float bf2f(unsigned short v) {
  return __uint_as_float((unsigned)v << 16);
}

// ---------------- gating: logits -> top2 -> weights + counts ----------------
__global__ __launch_bounds__(256) void gate_kernel(
    const float* __restrict__ x, const float* __restrict__ gw,
    int* __restrict__ counts, int* __restrict__ tok_e, float* __restrict__ tok_w)
{
  int lane = threadIdx.x & 63;
  int tok = blockIdx.x * 4 + (threadIdx.x >> 6);
  const float* xr = x + (size_t)tok * DDIM;
  float acc[NEXP];
#pragma unroll
  for (int e = 0; e < NEXP; ++e) acc[e] = 0.f;
  for (int i = 0; i < DDIM / 64; ++i) {
    int d = i * 64 + lane;
    float xv = xr[d];
    const float* g = gw + (size_t)d * NEXP;
#pragma unroll
    for (int e = 0; e < NEXP; ++e) acc[e] += xv * g[e];
  }
#pragma unroll
  for (int off = 32; off > 0; off >>= 1) {
#pragma unroll
    for (int e = 0; e < NEXP; ++e) acc[e] += __shfl_xor(acc[e], off);
  }
  if (lane == 0) {
    int i1 = 0; float m1 = acc[0];
#pragma unroll
    for (int e = 1; e < NEXP; ++e) if (acc[e] > m1) { m1 = acc[e]; i1 = e; }
    int i2 = -1; float m2 = -3.4e38f;
#pragma unroll
    for (int e = 0; e < NEXP; ++e) if (e != i1 && acc[e] > m2) { m2 = acc[e]; i2 = e; }
    float w1 = 1.f / (1.f + expf(m2 - m1));   // == p1/(p1+p2)
    tok_e[tok * 2] = i1; tok_e[tok * 2 + 1] = i2;
    tok_w[tok * 2] = w1; tok_w[tok * 2 + 1] = 1.f - w1;
    atomicAdd(&counts[i1], 1);
    atomicAdd(&counts[i2], 1);
  }
}

// ---------------- scan: padded offsets + tile table ----------------
__global__ void scan_kernel(const int* __restrict__ counts, int* padded_off,
                            int* tile_e, int* tile_row, int* numTiles)
{
  if (threadIdx.x == 0 && blockIdx.x == 0) {
    int off = 0, nt = 0;
    for (int e = 0; e < NEXP; ++e) {
      padded_off[e] = off;
      int c = counts[e];
      int ntile = (c + BM - 1) / BM;
      for (int i = 0; i < ntile; ++i) { tile_e[nt] = e; tile_row[nt] = off + i * BM; ++nt; }
      off += ntile * BM;
    }
    *numTiles = nt;
  }
}

__global__ void init_pairs(int* __restrict__ pair_token) {
  int i = blockIdx.x * 256 + threadIdx.x;
  if (i < PADMAX) pair_token[i] = -1;
}

__global__ void scatter_kernel(const int* __restrict__ tok_e,
                               const int* __restrict__ padded_off, int* __restrict__ fill,
                               int* __restrict__ pair_token, int* __restrict__ tok_slot)
{
  int tok = blockIdx.x * 256 + threadIdx.x;
  if (tok >= T_TOK) return;
#pragma unroll
  for (int k = 0; k < 2; ++k) {
    int e = tok_e[tok * 2 + k];
    int slot = padded_off[e] + atomicAdd(&fill[e], 1);
    pair_token[slot] = tok;
    tok_slot[tok * 2 + k] = slot;
  }
}

// ---------------- gather tokens -> bf16 rows (zeros for padding) ----------------
__global__ __launch_bounds__(256) void gather_x(
    const float* __restrict__ x, const int* __restrict__ pair_token,
    __hip_bfloat16* __restrict__ Xg)
{
  int gid = blockIdx.x * 256 + threadIdx.x;
  int r = gid >> 7;
  int c = (gid & 127) << 3;
  if (r >= PADMAX) return;
  int tk = pair_token[r];
  __hip_bfloat16 v[8];
  if (tk < 0) {
#pragma unroll
    for (int j = 0; j < 8; ++j) v[j] = __float2bfloat16(0.f);
  } else {
    const float* src = x + (size_t)tk * DDIM + c;
#pragma unroll
    for (int j = 0; j < 8; ++j) v[j] = __float2bfloat16(src[j]);
  }
  *(us8*)(Xg + (size_t)r * DDIM + c) = *(const us8*)v;
}

// ------- fp32 (R,C) -> bf16 (C,R) transpose+convert, per expert z, 64x64 tiles -------
__global__ __launch_bounds__(256) void transpose_conv(
    const float* __restrict__ in, __hip_bfloat16* __restrict__ out, int R, int C)
{
  __shared__ __hip_bfloat16 tile[64][68];
  size_t mat = (size_t)R * C;
  const float* ip = in + (size_t)blockIdx.z * mat;
  __hip_bfloat16* op = out + (size_t)blockIdx.z * mat;
  int c0 = blockIdx.x * 64, r0 = blockIdx.y * 64;
  int tx = threadIdx.x & 31, ty = threadIdx.x >> 5;   // 32 x 8
#pragma unroll
  for (int i = 0; i < 8; ++i) {
    int r = r0 + ty + i * 8;
    float2 v = *(const float2*)(ip + (size_t)r * C + c0 + tx * 2);
    tile[ty + i * 8][tx * 2]     = __float2bfloat16(v.x);
    tile[ty + i * 8][tx * 2 + 1] = __float2bfloat16(v.y);
  }
  __syncthreads();
#pragma unroll
  for (int i = 0; i < 8; ++i) {
    int cc = c0 + ty + i * 8;
    __hip_bfloat16 a = tile[tx * 2][ty + i * 8];
    __hip_bfloat16 b = tile[tx * 2 + 1][ty + i * 8];
    us4 dummy; (void)dummy;
    unsigned short ua = *(unsigned short*)&a, ub = *(unsigned short*)&b;
    unsigned int packed = (unsigned)ua | ((unsigned)ub << 16);
    *(unsigned int*)(op + (size_t)cc * R + r0 + tx * 2) = packed;
  }
}

// ---------------- pass A: H = gelu(Xg @ W1t[e]^T) ----------------
__global__ __launch_bounds__(256) void ffn1_kernel(
    const __hip_bfloat16* __restrict__ Xg, const __hip_bfloat16* __restrict__ W1t,
    __hip_bfloat16* __restrict__ H,
    const int* __restrict__ tile_e, const int* __restrict__ tile_row,
    const int* __restrict__ numTiles)
{
  if ((int)blockIdx.x >= *numTiles) return;
  __shared__ __align__(16) __hip_bfloat16 aS[BM * BKK];
  __shared__ __align__(16) __hip_bfloat16 bS[BN * BKK];
  int e = tile_e[blockIdx.x];
  int row0 = tile_row[blockIdx.x];
  int col0 = blockIdx.y * BN;
  int t = threadIdx.x, lane = t & 63, wid = t >> 6;
  int wr = (wid >> 1) * 64, wc = (wid & 1) * 64;
  int fr = lane & 15, fk = (lane >> 4) * 8;
  int xorv = (fr & 7) << 3;
  f32x4 acc[4][4] = {};
  const __hip_bfloat16* Ab = Xg + (size_t)row0 * DDIM;
  const __hip_bfloat16* Bb = W1t + ((size_t)e * FDIM + col0) * DDIM;
  int srow = t >> 3;
  int xcol = ((t & 7) ^ (srow & 7)) * 8;
  const __hip_bfloat16* aP = Ab + (size_t)srow * DDIM + xcol;
  const __hip_bfloat16* bP = Bb + (size_t)srow * DDIM + xcol;
  __hip_bfloat16* aD = aS + wid * 512;
  __hip_bfloat16* bD = bS + wid * 512;
  for (int kt = 0; kt < DDIM; kt += BKK) {
    __syncthreads();
#pragma unroll
    for (int i = 0; i < 4; ++i) GLOAD16(aD + i * 2048, aP + (size_t)i * 32 * DDIM + kt);
#pragma unroll
    for (int i = 0; i < 4; ++i) GLOAD16(bD + i * 2048, bP + (size_t)i * 32 * DDIM + kt);
    __syncthreads();
#pragma unroll
    for (int kk = 0; kk < 2; ++kk) {
      int ko = kk * 32 + fk;
      s16x8 af[4], bfv[4];
#pragma unroll
      for (int m = 0; m < 4; ++m)
        af[m] = *(const s16x8*)(aS + (wr + m * 16 + fr) * 64 + (ko ^ xorv));
#pragma unroll
      for (int n = 0; n < 4; ++n)
        bfv[n] = *(const s16x8*)(bS + (wc + n * 16 + fr) * 64 + (ko ^ xorv));
#pragma unroll
      for (int m = 0; m < 4; ++m)
#pragma unroll
        for (int n = 0; n < 4; ++n)
          acc[m][n] = __builtin_amdgcn_mfma_f32_16x16x32_bf16(af[m], bfv[n], acc[m][n], 0, 0, 0);
    }
  }
  int orow = (lane >> 4) * 4;
#pragma unroll
  for (int m = 0; m < 4; ++m) {
    int r = row0 + wr + m * 16 + orow;
#pragma unroll
    for (int j = 0; j < 4; ++j) {
#pragma unroll
      for (int n = 0; n < 4; ++n) {
        int c = col0 + wc + n * 16 + fr;
        H[(size_t)(r + j) * FDIM + c] = __float2bfloat16(gelu_tanh(acc[m][n][j]));
      }
    }
  }
}

// ---------------- pass B: Eout = H @ W2t[e]^T (per padded row) ----------------
__global__ __launch_bounds__(256) void ffn2_kernel(
    const __hip_bfloat16* __restrict__ H, const __hip_bfloat16* __restrict__ W2t,
    __hip_bfloat16* __restrict__ Eout,
    const int* __restrict__ tile_e, const int* __restrict__ tile_row,
    const int* __restrict__ numTiles)
{
  if ((int)blockIdx.x >= *numTiles) return;
  __shared__ __align__(16) __hip_bfloat16 aS[BM * BKK];
  __shared__ __align__(16) __hip_bfloat16 bS[BN * BKK];
  int e = tile_e[blockIdx.x];
  int row0 = tile_row[blockIdx.x];
  int col0 = blockIdx.y * BN;
  int t = threadIdx.x, lane = t & 63, wid = t >> 6;
  int wr = (wid >> 1) * 64, wc = (wid & 1) * 64;
  int fr = lane & 15, fk = (lane >> 4) * 8;
  int xorv = (fr & 7) << 3;
  f32x4 acc[4][4] = {};
  const __hip_bfloat16* Ab = H + (size_t)row0 * FDIM;
  const __hip_bfloat16* Bb = W2t + ((size_t)e * DDIM + col0) * FDIM;
  int srow = t >> 3;
  int xcol = ((t & 7) ^ (srow & 7)) * 8;
  const __hip_bfloat16* aP = Ab + (size_t)srow * FDIM + xcol;
  const __hip_bfloat16* bP = Bb + (size_t)srow * FDIM + xcol;
  __hip_bfloat16* aD = aS + wid * 512;
  __hip_bfloat16* bD = bS + wid * 512;
  for (int kt = 0; kt < FDIM; kt += BKK) {
    __syncthreads();
#pragma unroll
    for (int i = 0; i < 4; ++i) GLOAD16(aD + i * 2048, aP + (size_t)i * 32 * FDIM + kt);
#pragma unroll
    for (int i = 0; i < 4; ++i) GLOAD16(bD + i * 2048, bP + (size_t)i * 32 * FDIM + kt);
    __syncthreads();
#pragma unroll
    for (int kk = 0; kk < 2; ++kk) {
      int ko = kk * 32 + fk;
      s16x8 af[4], bfv[4];
#pragma unroll
      for (int m = 0; m < 4; ++m)
        af[m] = *(const s16x8*)(aS + (wr + m * 16 + fr) * 64 + (ko ^ xorv));
#pragma unroll
      for (int n = 0; n < 4; ++n)
        bfv[n] = *(const s16x8*)(bS + (wc + n * 16 + fr) * 64 + (ko ^ xorv));
#pragma unroll
      for (int m = 0; m < 4; ++m)
#pragma unroll
        for (int n = 0; n < 4; ++n)
          acc[m][n] = __builtin_amdgcn_mfma_f32_16x16x32_bf16(af[m], bfv[n], acc[m][n], 0, 0, 0);
    }
  }
  int orow = (lane >> 4) * 4;
#pragma unroll
  for (int m = 0; m < 4; ++m) {
    int r = row0 + wr + m * 16 + orow;
#pragma unroll
    for (int j = 0; j < 4; ++j) {
#pragma unroll
      for (int n = 0; n < 4; ++n) {
        int c = col0 + wc + n * 16 + fr;
        Eout[(size_t)(r + j) * DDIM + c] = __float2bfloat16(acc[m][n][j]);
      }
    }
  }
}

// ---------------- combine: out[tok] = wa*Eout[sa] + wb*Eout[sb] ----------------
__global__ __launch_bounds__(256) void combine_kernel(
    const __hip_bfloat16* __restrict__ Eout, const int* __restrict__ tok_slot,
    const float* __restrict__ tok_w, float* __restrict__ out)
{
  int tok = blockIdx.x;
  int sa = tok_slot[tok * 2], sb = tok_slot[tok * 2 + 1];
  float wa = tok_w[tok * 2], wb = tok_w[tok * 2 + 1];
  const __hip_bfloat16* ra = Eout + (size_t)sa * DDIM;
  const __hip_bfloat16* rb = Eout + (size_t)sb * DDIM;
  float* op = out + (size_t)tok * DDIM;
  int c = threadIdx.x * 4;
  us4 va = *(const us4*)(ra + c);
  us4 vb = *(const us4*)(rb + c);
  float4 o;
  o.x = wa * bf2f(va.x) + wb * bf2f(vb.x);
  o.y = wa * bf2f(va.y) + wb * bf2f(vb.y);
  o.z = wa * bf2f(va.z) + wb * bf2f(vb.z);
  o.w = wa * bf2f(va.w) + wb * bf2f(vb.w);
  *(float4*)(op + c) = o;
}

extern "C" void kernel_launch(void* const* d_in, const int* in_sizes, int n_in,
                              void* d_out, int out_size, void* d_ws, size_t ws_size,
                              hipStream_t stream)
{
  const float* x      = (const float*)d_in[0];
  const float* gate_w = (const float*)d_in[1];
  const float* w1     = (const float*)d_in[2];
  const float* w2     = (const float*)d_in[3];
  float* out = (float*)d_out;

  char* ws = (char*)d_ws;
  size_t off = 0;
  auto alloc = [&](size_t bytes) -> void* {
    void* p = ws + off;
    off = (off + bytes + 255) & ~(size_t)255;
    return p;
  };
  int*   counts     = (int*)alloc(NEXP * 4);      // first 1 KiB = control block
  int*   fill       = (int*)alloc(NEXP * 4);
  int*   padded_off = (int*)alloc(NEXP * 4);
  int*   numTiles   = (int*)alloc(4);
  int*   tile_e     = (int*)alloc(MAXT * 4);
  int*   tile_row   = (int*)alloc(MAXT * 4);
  int*   tok_e      = (int*)alloc((size_t)T_TOK * 2 * 4);
  float* tok_w      = (float*)alloc((size_t)T_TOK * 2 * 4);
  int*   tok_slot   = (int*)alloc((size_t)T_TOK * 2 * 4);
  int*   pair_token = (int*)alloc((size_t)PADMAX * 4);
  __hip_bfloat16* XgEout = (__hip_bfloat16*)alloc((size_t)PADMAX * DDIM * 2); // Xg, later Eout
  __hip_bfloat16* W1t  = (__hip_bfloat16*)alloc((size_t)NEXP * FDIM * DDIM * 2);
  __hip_bfloat16* W2t  = (__hip_bfloat16*)alloc((size_t)NEXP * FDIM * DDIM * 2);
  __hip_bfloat16* Hbuf = (__hip_bfloat16*)alloc((size_t)PADMAX * FDIM * 2);
  (void)in_sizes; (void)n_in; (void)ws_size; (void)out_size;

  hipMemsetAsync(d_ws, 0, 1024, stream);   // counts/fill/padded_off/numTiles

  transpose_conv<<<dim3(FDIM / 64, DDIM / 64, NEXP), 256, 0, stream>>>(w1, W1t, DDIM, FDIM);
  transpose_conv<<<dim3(DDIM / 64, FDIM / 64, NEXP), 256, 0, stream>>>(w2, W2t, FDIM, DDIM);

  gate_kernel<<<T_TOK / 4, 256, 0, stream>>>(x, gate_w, counts, tok_e, tok_w);
  scan_kernel<<<1, 64, 0, stream>>>(counts, padded_off, tile_e, tile_row, numTiles);
  init_pairs<<<(PADMAX + 255) / 256, 256, 0, stream>>>(pair_token);
  scatter_kernel<<<T_TOK / 256, 256, 0, stream>>>(tok_e, padded_off, fill,
                                                  pair_token, tok_slot);
  gather_x<<<(PADMAX * (DDIM / 8) + 255) / 256, 256, 0, stream>>>(x, pair_token, XgEout);

  ffn1_kernel<<<dim3(MAXT, FDIM / BN), 256, 0, stream>>>(XgEout, W1t, Hbuf,
                                                         tile_e, tile_row, numTiles);
  ffn2_kernel<<<dim3(MAXT, DDIM / BN), 256, 0, stream>>>(Hbuf, W2t, XgEout,
                                                         tile_e, tile_row, numTiles);
  combine_kernel<<<T_TOK, 256, 0, stream>>>(XgEout, tok_slot, tok_w, out);
}